// Round 14
// baseline (653.926 us; speedup 1.0000x reference)
//
#include <hip/hip_runtime.h>
#include <cstdint>
#include <cstddef>

typedef float  f32x4  __attribute__((ext_vector_type(4)));
typedef __bf16 bf16x8 __attribute__((ext_vector_type(8)));
typedef unsigned short u16x8 __attribute__((ext_vector_type(8)));
typedef unsigned short u16x4 __attribute__((ext_vector_type(4)));
typedef unsigned short u16x2 __attribute__((ext_vector_type(2)));

#define DEV static __device__ __forceinline__

DEV unsigned short f2bfu(float f) { __bf16 b = (__bf16)f; return __builtin_bit_cast(unsigned short, b); }
DEV float bfu2f(unsigned short u) { return (float)__builtin_bit_cast(__bf16, u); }
DEV bf16x8 ldb8(const void* p) { return __builtin_bit_cast(bf16x8, *(const u16x8*)p); }
DEV float fexp(float x) { return __builtin_amdgcn_exp2f(x * 1.44269504f); }
DEV float fexp2(float x) { return __builtin_amdgcn_exp2f(x); }

DEV f32x4 mfma16(bf16x8 a, bf16x8 b, f32x4 c) {
  return __builtin_amdgcn_mfma_f32_16x16x32_bf16(a, b, c, 0, 0, 0);
}

DEV void gload16(const void* g, void* l) {
  __builtin_amdgcn_global_load_lds((const unsigned int*)g, (unsigned int*)l, 16, 0, 0);
}

#define FENCE() asm volatile("" ::: "memory")
#define LGKM0() asm volatile("s_waitcnt lgkmcnt(0)" ::: "memory")
#define LGKM4() asm volatile("s_waitcnt lgkmcnt(4)" ::: "memory")
#define VMC8()  asm volatile("s_waitcnt vmcnt(8)" ::: "memory")
#define VMC4()  asm volatile("s_waitcnt vmcnt(4)" ::: "memory")
#define VMC0()  asm volatile("s_waitcnt vmcnt(0)" ::: "memory")
#define SBAR()  __builtin_amdgcn_s_barrier()
#define SCH0()  __builtin_amdgcn_sched_barrier(0)
#define PRIO1() __builtin_amdgcn_s_setprio(1)
#define PRIO0() __builtin_amdgcn_s_setprio(0)

// ---------------------------------------------------------------------------
// Weight conversion kernels (f32 -> bf16), run once per call.
// ---------------------------------------------------------------------------
__global__ __launch_bounds__(256) void conv_cat3(
    const float* __restrict__ s0, const float* __restrict__ s1,
    const float* __restrict__ s2, unsigned short* __restrict__ d)
{
  size_t i = (size_t)blockIdx.x * 256 + threadIdx.x;
  size_t e = i * 4;
  const float* s = e < 4194304 ? s0 : (e < 8388608 ? s1 : s2);
  f32x4 v = *(const f32x4*)(s + (e & 4194303));
  u16x4 o = { f2bfu(v.x), f2bfu(v.y), f2bfu(v.z), f2bfu(v.w) };
  *(u16x4*)(d + e) = o;
}

__global__ __launch_bounds__(256) void conv_plain(
    const float* __restrict__ s, unsigned short* __restrict__ d)
{
  size_t e = ((size_t)blockIdx.x * 256 + threadIdx.x) * 4;
  f32x4 v = *(const f32x4*)(s + e);
  u16x4 o = { f2bfu(v.x), f2bfu(v.y), f2bfu(v.z), f2bfu(v.w) };
  *(u16x4*)(d + e) = o;
}

// interleave w1/w3 rows in 16-row groups: logical row n -> grp=n>>4 even: w1,
// odd: w3, source row (grp>>1)*16 + (n&15). Pads to N=11008 with clamp.
__global__ __launch_bounds__(256) void conv_w13(
    const float* __restrict__ w1, const float* __restrict__ w3,
    unsigned short* __restrict__ d)
{
  size_t i = (size_t)blockIdx.x * 256 + threadIdx.x;
  size_t e = i * 4;
  if (e >= 22544384ull) return;
  int n = (int)(e >> 11), kc = (int)(e & 2047);
  int grp = n >> 4;
  int srcrow = (grp >> 1) * 16 + (n & 15);
  if (srcrow >= 5440) srcrow = 5439;
  const float* s = (grp & 1) ? w3 : w1;
  size_t off = (size_t)srcrow * 2048 + kc;
  f32x4 v = *(const f32x4*)(s + off);
  u16x4 o = { f2bfu(v.x), f2bfu(v.y), f2bfu(v.z), f2bfu(v.w) };
  *(u16x4*)(d + e) = o;
}

// ---------------------------------------------------------------------------
// gemm_p: 128x128 tile, deep pipeline. BK=64 in two 32-col halves, each half
// double-buffered; 2 phases/K-tile, counted vmcnt(4).
// EPI 0: QKV fused + RoPE; EPI 1: OPROJ f32 D0=auxf+acc; EPI 3: W2ACC D0+=acc
// ---------------------------------------------------------------------------
template<int EPI>
__global__ __launch_bounds__(256) void gemm_p(
    const unsigned short* __restrict__ A, const unsigned short* __restrict__ B,
    void* __restrict__ D0, void* __restrict__ D1, void* __restrict__ D2,
    const float* __restrict__ auxf, const float* __restrict__ cosT,
    const float* __restrict__ sinT, int M, int N, int K)
{
  __shared__ __align__(16) char Asb[4 * 8192];   // [kh*2+db]
  __shared__ __align__(16) char Bsb[4 * 8192];

  const int tid = threadIdx.x, lane = tid & 63, w = tid >> 6;
  const int wr = w >> 1, wc = w & 1, l15 = lane & 15, lg = lane >> 4;
  const int m0 = blockIdx.x * 128, n0 = blockIdx.y * 128;

  const int srow = tid >> 2, s4 = tid & 3;
  const int s4s = s4 ^ ((srow >> 1) & 3);
  const unsigned short* As0 = A + (size_t)(m0 + srow) * K + s4s * 8;
  const unsigned short* As1 = A + (size_t)(m0 + 64 + srow) * K + s4s * 8;
  const unsigned short* Bs0 = B + (size_t)(n0 + srow) * K + s4s * 8;
  const unsigned short* Bs1 = B + (size_t)(n0 + 64 + srow) * K + s4s * 8;
  const int dst0 = tid * 16, dst1 = 4096 + tid * 16;

#define STG_A(kh, db, kt) do { char* r = Asb + ((kh)*2+(db))*8192;            \
    gload16(As0 + (size_t)(kt)*64 + (kh)*32, r + dst0);                        \
    gload16(As1 + (size_t)(kt)*64 + (kh)*32, r + dst1); } while(0)
#define STG_B(kh, db, kt) do { char* r = Bsb + ((kh)*2+(db))*8192;            \
    gload16(Bs0 + (size_t)(kt)*64 + (kh)*32, r + dst0);                        \
    gload16(Bs1 + (size_t)(kt)*64 + (kh)*32, r + dst1); } while(0)

  f32x4 zero = {0.f, 0.f, 0.f, 0.f};
  f32x4 acc[4][4];
#pragma unroll
  for (int i = 0; i < 4; i++)
#pragma unroll
    for (int j = 0; j < 4; j++) acc[i][j] = zero;

  int aro[4], bro[4];
#pragma unroll
  for (int mi = 0; mi < 4; mi++) {
    int row = wr * 64 + mi * 16 + l15;
    aro[mi] = row * 64 + ((lg ^ ((row >> 1) & 3)) << 4);
  }
#pragma unroll
  for (int ni = 0; ni < 4; ni++) {
    int row = wc * 64 + ni * 16 + l15;
    bro[ni] = row * 64 + ((lg ^ ((row >> 1) & 3)) << 4);
  }

  const int nkt = K >> 6;

  STG_A(0, 0, 0); STG_B(0, 0, 0); STG_A(1, 0, 0); STG_B(1, 0, 0);

  for (int t = 0; t < nkt; ++t) {
    const int db = t & 1, dn = db ^ 1;
    const bool pf = (t + 1) < nkt;
    const char* Ar0 = Asb + (0 * 2 + db) * 8192;
    const char* Br0 = Bsb + (0 * 2 + db) * 8192;
    const char* Ar1 = Asb + (1 * 2 + db) * 8192;
    const char* Br1 = Bsb + (1 * 2 + db) * 8192;

    VMC4(); FENCE(); SBAR();
    bf16x8 af[4], bfr[4];
#pragma unroll
    for (int ni = 0; ni < 4; ni++) bfr[ni] = ldb8(Br0 + bro[ni]);
#pragma unroll
    for (int mi = 0; mi < 4; mi++) af[mi] = ldb8(Ar0 + aro[mi]);
    if (pf) { STG_A(0, dn, t + 1); STG_B(0, dn, t + 1); }
    LGKM0(); SCH0();
    PRIO1();
#pragma unroll
    for (int mi = 0; mi < 4; mi++)
#pragma unroll
      for (int ni = 0; ni < 4; ni++)
        acc[mi][ni] = mfma16(af[mi], bfr[ni], acc[mi][ni]);
    PRIO0();

    if (pf) { VMC4(); } else { VMC0(); }
    FENCE(); SBAR();
#pragma unroll
    for (int ni = 0; ni < 4; ni++) bfr[ni] = ldb8(Br1 + bro[ni]);
#pragma unroll
    for (int mi = 0; mi < 4; mi++) af[mi] = ldb8(Ar1 + aro[mi]);
    if (pf) { STG_A(1, dn, t + 1); STG_B(1, dn, t + 1); }
    LGKM0(); SCH0();
    PRIO1();
#pragma unroll
    for (int mi = 0; mi < 4; mi++)
#pragma unroll
      for (int ni = 0; ni < 4; ni++)
        acc[mi][ni] = mfma16(af[mi], bfr[ni], acc[mi][ni]);
    PRIO0();
  }
#undef STG_A
#undef STG_B

  if constexpr (EPI == 0) {
    unsigned short* qd = (unsigned short*)D0;
    unsigned short* kd = (unsigned short*)D1;
    unsigned short* vd = (unsigned short*)D2;
#pragma unroll
    for (int mi = 0; mi < 4; mi++) {
#pragma unroll
      for (int ni = 0; ni < 4; ni++) {
        int col = n0 + wc * 64 + ni * 16 + l15;
#pragma unroll
        for (int r = 0; r < 4; r++) {
          int row = m0 + wr * 64 + mi * 16 + lg * 4 + r;
          float v = acc[mi][ni][r];
          if (col < 4096) {
            int d = col & 127, pi = d >> 1, sp = row & 2047;
            float c = cosT[sp * 64 + pi], s = sinT[sp * 64 + pi];
            float part = __shfl_xor(v, 1);
            float res = (d & 1) ? (part * s + v * c) : (v * c - part * s);
            unsigned short* dst = (col < 2048) ? qd : kd;
            dst[(size_t)row * 2048 + (col & 2047)] = f2bfu(res);
          } else {
            int vdc = col - 4096;
            vd[((size_t)((row >> 11) * 2048 + vdc)) * 2048 + (row & 2047)] = f2bfu(v);
          }
        }
      }
    }
  } else {
    float* O = (float*)D0;
#pragma unroll
    for (int mi = 0; mi < 4; mi++)
#pragma unroll
      for (int ni = 0; ni < 4; ni++) {
        int col = n0 + wc * 64 + ni * 16 + l15;
#pragma unroll
        for (int r = 0; r < 4; r++) {
          int row = m0 + wr * 64 + mi * 16 + lg * 4 + r;
          size_t ix = (size_t)row * 2048 + col;
          if constexpr (EPI == 1) O[ix] = auxf[ix] + acc[mi][ni][r];
          else                    O[ix] = O[ix] + acc[mi][ni][r];
        }
      }
  }
}

// ---------------------------------------------------------------------------
// gemm8v2 + counted-lgkm ds_read pipelining (m201 micro-technique):
// all 12 ds_reads of a K-half issued up front; lgkmcnt(4) before the first
// MFMA quadrant (A-hi reads complete under it); lgkmcnt(0) before the second.
// Barrier/vmcnt structure identical to the proven round-6 form.
// EPI 2: GATE13 silu(a)*c epilogue.
// ---------------------------------------------------------------------------
template<int EPI>
__global__ __launch_bounds__(512, 1) void gemm8v2(
    const unsigned short* __restrict__ A, const unsigned short* __restrict__ B,
    void* __restrict__ D0, int M, int N, int K)
{
  __shared__ __align__(16) char Asb[4 * 16384];   // [kh*2+db]
  __shared__ __align__(16) char Bsb[4 * 16384];

  const int tid = threadIdx.x, lane = tid & 63, w = tid >> 6;
  const int wm = w >> 2, wn = w & 3;
  const int l15 = lane & 15, lg = lane >> 4;

  const int nwg = gridDim.x, chunk = nwg >> 3;
  const int wg = (blockIdx.x & 7) * chunk + (blockIdx.x >> 3);
  const int MT = M >> 8;
  const int mt = wg % MT, nt = wg / MT;
  const int m0 = mt * 256, n0 = nt * 256;

  const int srow = tid >> 2;
  const int s4   = tid & 3;
  const int s4s  = s4 ^ ((srow >> 1) & 3);
  const unsigned short* As0 = A + (size_t)(m0 + srow) * K + s4s * 8;
  const unsigned short* As1 = A + (size_t)(m0 + 128 + srow) * K + s4s * 8;
  const unsigned short* Bs0 = B + (size_t)(n0 + srow) * K + s4s * 8;
  const unsigned short* Bs1 = B + (size_t)(n0 + 128 + srow) * K + s4s * 8;
  const int dst0 = tid * 16, dst1 = 8192 + tid * 16;

#define STAGE_A(kh, db, kt) do { char* rgn = Asb + ((kh)*2+(db))*16384;       \
    gload16(As0 + (size_t)(kt)*64 + (kh)*32, rgn + dst0);                      \
    gload16(As1 + (size_t)(kt)*64 + (kh)*32, rgn + dst1); } while(0)
#define STAGE_B(kh, db, kt) do { char* rgn = Bsb + ((kh)*2+(db))*16384;       \
    gload16(Bs0 + (size_t)(kt)*64 + (kh)*32, rgn + dst0);                      \
    gload16(Bs1 + (size_t)(kt)*64 + (kh)*32, rgn + dst1); } while(0)

  f32x4 zero = {0.f, 0.f, 0.f, 0.f};
  f32x4 acc[8][4];
#pragma unroll
  for (int i = 0; i < 8; i++)
#pragma unroll
    for (int j = 0; j < 4; j++) acc[i][j] = zero;

  int aro[8], bro[4];
#pragma unroll
  for (int mi = 0; mi < 8; mi++) {
    int row = wm * 128 + mi * 16 + l15;
    aro[mi] = row * 64 + ((lg ^ ((row >> 1) & 3)) << 4);
  }
#pragma unroll
  for (int ni = 0; ni < 4; ni++) {
    int row = wn * 64 + ni * 16 + l15;
    bro[ni] = row * 64 + ((lg ^ ((row >> 1) & 3)) << 4);
  }

  const int nkt = K >> 6;

  STAGE_A(0, 0, 0); STAGE_B(0, 0, 0); STAGE_A(1, 0, 0); STAGE_B(1, 0, 0);

  for (int t = 0; t < nkt; ++t) {
    const int db = t & 1, dn = db ^ 1;
    const bool pf = (t + 1) < nkt;
    const char* Ar0 = Asb + (0 * 2 + db) * 16384;
    const char* Br0 = Bsb + (0 * 2 + db) * 16384;
    const char* Ar1 = Asb + (1 * 2 + db) * 16384;
    const char* Br1 = Bsb + (1 * 2 + db) * 16384;

    // ---- K-half 0: issue all 12 ds_reads, counted lgkm
    VMC4(); FENCE(); SBAR();
    bf16x8 bfr[4], af[4], ag[4];
#pragma unroll
    for (int ni = 0; ni < 4; ni++) bfr[ni] = ldb8(Br0 + bro[ni]);
#pragma unroll
    for (int mi = 0; mi < 4; mi++) af[mi] = ldb8(Ar0 + aro[mi]);
#pragma unroll
    for (int mi = 0; mi < 4; mi++) ag[mi] = ldb8(Ar0 + aro[mi + 4]);
    if (pf) STAGE_A(0, dn, t + 1);
    LGKM4(); SCH0();
    PRIO1();
#pragma unroll
    for (int mi = 0; mi < 4; mi++)
#pragma unroll
      for (int ni = 0; ni < 4; ni++)
        acc[mi][ni] = mfma16(af[mi], bfr[ni], acc[mi][ni]);
    PRIO0();
    if (pf) STAGE_B(0, dn, t + 1);
    LGKM0(); SCH0();
    PRIO1();
#pragma unroll
    for (int mi = 0; mi < 4; mi++)
#pragma unroll
      for (int ni = 0; ni < 4; ni++)
        acc[mi + 4][ni] = mfma16(ag[mi], bfr[ni], acc[mi + 4][ni]);
    PRIO0();

    // ---- K-half 1
    if (pf) { VMC4(); } else { VMC0(); }
    FENCE(); SBAR();
#pragma unroll
    for (int ni = 0; ni < 4; ni++) bfr[ni] = ldb8(Br1 + bro[ni]);
#pragma unroll
    for (int mi = 0; mi < 4; mi++) af[mi] = ldb8(Ar1 + aro[mi]);
#pragma unroll
    for (int mi = 0; mi < 4; mi++) ag[mi] = ldb8(Ar1 + aro[mi + 4]);
    if (pf) STAGE_A(1, dn, t + 1);
    LGKM4(); SCH0();
    PRIO1();
#pragma unroll
    for (int mi = 0; mi < 4; mi++)
#pragma unroll
      for (int ni = 0; ni < 4; ni++)
        acc[mi][ni] = mfma16(af[mi], bfr[ni], acc[mi][ni]);
    PRIO0();
    if (pf) STAGE_B(1, dn, t + 1);
    LGKM0(); SCH0();
    PRIO1();
#pragma unroll
    for (int mi = 0; mi < 4; mi++)
#pragma unroll
      for (int ni = 0; ni < 4; ni++)
        acc[mi + 4][ni] = mfma16(ag[mi], bfr[ni], acc[mi + 4][ni]);
    PRIO0();
  }
#undef STAGE_A
#undef STAGE_B

  if constexpr (EPI == 2) {
    unsigned short* G = (unsigned short*)D0;
#pragma unroll
    for (int mi = 0; mi < 8; mi++)
#pragma unroll
      for (int nj = 0; nj < 2; nj++) {
        int outc = (nt * 8 + wn * 2 + nj) * 16 + l15;
        if (outc >= 5440) continue;
#pragma unroll
        for (int r = 0; r < 4; r++) {
          int row = m0 + wm * 128 + mi * 16 + lg * 4 + r;
          float a = acc[mi][2 * nj][r];
          float c = acc[mi][2 * nj + 1][r];
          float sg = a / (1.0f + fexp(-a));
          G[(size_t)row * 5440 + outc] = f2bfu(sg * c);
        }
      }
  }
}

// ---------------------------------------------------------------------------
// RMSNorm v2: wave-shuffle reduce + one barrier.
// ---------------------------------------------------------------------------
__global__ __launch_bounds__(256) void rmsnorm_k(
    const float* __restrict__ x, const float* __restrict__ g,
    unsigned short* __restrict__ out)
{
  int row = blockIdx.x, t = threadIdx.x;
  const int w = t >> 6;
  const float* xr = x + (size_t)row * 2048;
  f32x4 v0 = ((const f32x4*)xr)[t];
  f32x4 v1 = ((const f32x4*)xr)[t + 256];
  float ss = v0.x*v0.x + v0.y*v0.y + v0.z*v0.z + v0.w*v0.w
           + v1.x*v1.x + v1.y*v1.y + v1.z*v1.z + v1.w*v1.w;
#pragma unroll
  for (int off = 1; off < 64; off <<= 1) ss += __shfl_xor(ss, off);
  __shared__ float red[4];
  if ((t & 63) == 0) red[w] = ss;
  __syncthreads();
  float tot = red[0] + red[1] + red[2] + red[3];
  float rinv = rsqrtf(tot * (1.0f / 2048.0f) + 1e-5f);
  f32x4 g0 = ((const f32x4*)g)[t];
  f32x4 g1 = ((const f32x4*)g)[t + 256];
  u16x4 o0 = { f2bfu(v0.x*rinv*g0.x), f2bfu(v0.y*rinv*g0.y),
               f2bfu(v0.z*rinv*g0.z), f2bfu(v0.w*rinv*g0.w) };
  u16x4 o1 = { f2bfu(v1.x*rinv*g1.x), f2bfu(v1.y*rinv*g1.y),
               f2bfu(v1.z*rinv*g1.z), f2bfu(v1.w*rinv*g1.w) };
  *(u16x4*)(out + (size_t)row * 2048 + t * 4) = o0;
  *(u16x4*)(out + (size_t)row * 2048 + 1024 + t * 4) = o1;
}

__global__ __launch_bounds__(256) void rope_tab(float* __restrict__ cosT,
                                                float* __restrict__ sinT)
{
  int idx = blockIdx.x * 256 + threadIdx.x;
  int s = idx >> 6, p = idx & 63;
  float ang = (float)s * powf(10000.0f, -(float)p / 64.0f);
  cosT[idx] = cosf(ang);
  sinT[idx] = sinf(ang);
}

// ---------------------------------------------------------------------------
// Flash attention (R10 best-known form). Causal, swapped QK^T, KVBLK=64,
// 4 waves/block, paired q-tiles {bx, 31-bx}, K/V via global_load_lds into
// dbuf LDS, counted vmcnt(8), setprio on MFMA. Raw-score softmax
// (C = scale*log2e folded into exp2); defer-max (T13); rcp epilogue.
// ---------------------------------------------------------------------------
__global__ __launch_bounds__(256) void attn_fwd(
    const unsigned short* __restrict__ q, const unsigned short* __restrict__ k,
    const unsigned short* __restrict__ vt, unsigned short* __restrict__ o)
{
  const int S = 2048, Dm = 2048;
  const int tid  = threadIdx.x;
  const int lane = tid & 63;
  const int w    = tid >> 6;
  const int hh   = blockIdx.y, b = blockIdx.z;
  const int l15  = lane & 15, lg = lane >> 4;
  const float C = 0.08838834764831845f * 1.44269504f;  // scale * log2(e)

  __shared__ __align__(16) char Ksb[2][16384];
  __shared__ __align__(16) char Vsb[2][16384];
  __shared__ __align__(16) unsigned short Ps[4][16 * 76];

  const unsigned short* kg = k  + ((size_t)(b * S)) * Dm + hh * 128;
  const unsigned short* vg = vt + ((size_t)((b * 16 + hh) * 128)) * S;

  const int krs = tid >> 4, ksp = (tid & 15) ^ (krs & 7);
  const int vrs = tid >> 3, vsp = (tid & 7) ^ (vrs & 7);

#define STAGE_KV(j, buf) do {                                                  \
    int kv_ = (j) * 64;                                                        \
    _Pragma("unroll")                                                          \
    for (int rr = 0; rr < 4; rr++)                                             \
      gload16(kg + (size_t)(kv_ + rr * 16 + krs) * 2048 + ksp * 8,             \
              Ksb[buf] + (rr * 256 + tid) * 16);                               \
    _Pragma("unroll")                                                          \
    for (int rr = 0; rr < 4; rr++)                                             \
      gload16(vg + (size_t)(rr * 32 + vrs) * 2048 + kv_ + vsp * 8,             \
              Vsb[buf] + (rr * 256 + tid) * 16);                               \
  } while (0)

  for (int half = 0; half < 2; ++half) {
    const int qt = half ? (31 - blockIdx.x) : blockIdx.x;
    const int r0 = qt * 64;
    const int myq = r0 + w * 16 + l15;

    STAGE_KV(0, 0);

    bf16x8 qf[4];
    size_t qbase = ((size_t)(b * S + r0 + w * 16 + l15)) * Dm + hh * 128 + lg * 8;
#pragma unroll
    for (int kk = 0; kk < 4; kk++) qf[kk] = ldb8(q + qbase + kk * 32);

    f32x4 zero = {0.f, 0.f, 0.f, 0.f};
    f32x4 accO[8];
#pragma unroll
    for (int dt = 0; dt < 8; dt++) accO[dt] = zero;
    float mrun = -1e30f, lrun = 0.f;   // RAW (unscaled) units

    int ntile = qt + 1;
    for (int j = 0; j < ntile; ++j) {
      int kv0 = j * 64;
      const int db = j & 1;
      const bool pf = (j + 1) < ntile;
      if (pf) STAGE_KV(j + 1, db ^ 1);
      if (pf) { VMC8(); } else { VMC0(); }
      FENCE(); SBAR();

      const char* Ks = Ksb[db];
      const char* Vs = Vsb[db];

      f32x4 sfr[4];
#pragma unroll
      for (int sv = 0; sv < 4; sv++) sfr[sv] = zero;
      PRIO1();
#pragma unroll
      for (int kk = 0; kk < 4; kk++) {
#pragma unroll
        for (int sv = 0; sv < 4; sv++) {
          int row = sv * 16 + l15;
          int boff = (row * 256 + kk * 64 + lg * 16) ^ ((row & 7) << 4);
          bf16x8 kf = ldb8(Ks + boff);
          sfr[sv] = mfma16(kf, qf[kk], sfr[sv]);
        }
      }
      PRIO0();

      float tmax = -1e30f;
#pragma unroll
      for (int sv = 0; sv < 4; sv++)
#pragma unroll
        for (int r = 0; r < 4; r++) {
          int kvv = kv0 + sv * 16 + lg * 4 + r;
          float val = (kvv <= myq) ? sfr[sv][r] : -1e30f;
          sfr[sv][r] = val;
          tmax = fmaxf(tmax, val);
        }
      tmax = fmaxf(tmax, __shfl_xor(tmax, 16));
      tmax = fmaxf(tmax, __shfl_xor(tmax, 32));

      if (!__all(tmax <= mrun + 64.0f)) {
        float mnew = fmaxf(mrun, tmax);
        float alpha = fexp2((mrun - mnew) * C);
        lrun *= alpha;
        mrun = mnew;
        float al[4];
#pragma unroll
        for (int r = 0; r < 4; r++)
          al[r] = __shfl(alpha, (lane & 48) + lg * 4 + r);
#pragma unroll
        for (int dt = 0; dt < 8; dt++) {
          f32x4 t = accO[dt];
          t[0] *= al[0]; t[1] *= al[1]; t[2] *= al[2]; t[3] *= al[3];
          accO[dt] = t;
        }
      }

      float psum = 0.f;
#pragma unroll
      for (int sv = 0; sv < 4; sv++)
#pragma unroll
        for (int r = 0; r < 4; r++) {
          float pvv = fexp2((sfr[sv][r] - mrun) * C);
          sfr[sv][r] = pvv;
          psum += pvv;
        }
      psum += __shfl_xor(psum, 16);
      psum += __shfl_xor(psum, 32);
      lrun += psum;

#pragma unroll
      for (int sv = 0; sv < 4; sv++) {
        u16x2 lo = { f2bfu(sfr[sv][0]), f2bfu(sfr[sv][1]) };
        u16x2 hi = { f2bfu(sfr[sv][2]), f2bfu(sfr[sv][3]) };
        *(u16x2*)&Ps[w][l15 * 76 + sv * 16 + lg * 4]     = lo;
        *(u16x2*)&Ps[w][l15 * 76 + sv * 16 + lg * 4 + 2] = hi;
      }

      bf16x8 pa[2];
      pa[0] = ldb8(&Ps[w][l15 * 76 + lg * 8]);
      pa[1] = ldb8(&Ps[w][l15 * 76 + 32 + lg * 8]);
      PRIO1();
#pragma unroll
      for (int dt = 0; dt < 8; dt++) {
#pragma unroll
        for (int kk = 0; kk < 2; kk++) {
          int row = dt * 16 + l15;
          int boff = (row * 128 + kk * 64 + lg * 16) ^ ((row & 7) << 4);
          bf16x8 vb = ldb8(Vs + boff);
          accO[dt] = mfma16(pa[kk], vb, accO[dt]);
        }
      }
      PRIO0();
      FENCE(); SBAR();
    }

    float lf[4];
#pragma unroll
    for (int r = 0; r < 4; r++) {
      float lv = __shfl(lrun, (lane & 48) + lg * 4 + r);
      lf[r] = __builtin_amdgcn_rcpf(lv);
    }
#pragma unroll
    for (int dt = 0; dt < 8; dt++) {
#pragma unroll
      for (int r = 0; r < 4; r++) {
        int qr = r0 + w * 16 + lg * 4 + r;
        o[((size_t)(b * S + qr)) * Dm + hh * 128 + dt * 16 + l15] =
            f2bfu(accO[dt][r] * lf[r]);
      }
    }
  }
#undef STAGE_KV
}

// ---------------------------------------------------------------------------
extern "C" void kernel_launch(void* const* d_in, const int* in_sizes, int n_in,
                              void* d_out, int out_size, void* d_ws, size_t ws_size,
                              hipStream_t stream)
{
  const float* x      = (const float*)d_in[0];
  const float* wq     = (const float*)d_in[1];
  const float* wk     = (const float*)d_in[2];
  const float* wv     = (const float*)d_in[3];
  const float* wo     = (const float*)d_in[4];
  const float* w1     = (const float*)d_in[5];
  const float* w2     = (const float*)d_in[6];
  const float* w3     = (const float*)d_in[7];
  const float* g_attn = (const float*)d_in[8];
  const float* g_ffn  = (const float*)d_in[9];
  float* out = (float*)d_out;

  unsigned short* W = (unsigned short*)d_ws;
  unsigned short* h_bf    = W;                      // 8388608
  unsigned short* q_bf    = W + 8388608ull;
  unsigned short* k_bf    = W + 16777216ull;
  unsigned short* vt_bf   = W + 25165824ull;
  unsigned short* o_bf    = W + 33554432ull;
  unsigned short* wqkv_bf = W + 41943040ull;        // 12582912
  unsigned short* wo_bf   = W + 54525952ull;        // 4194304
  unsigned short* w13_bf  = W + 58720256ull;        // 22544384 (11008 x 2048)
  unsigned short* w2_bf   = W + 81264640ull;        // 11141120
  unsigned short* a1_bf   = q_bf;                   // alias: q/k/vt dead by then
  float* cosT = (float*)o_bf;                       // consumed before o written
  float* sinT = cosT + 131072;

  dim3 blk(256);
  rope_tab<<<512, blk, 0, stream>>>(cosT, sinT);
  conv_cat3<<<12288, blk, 0, stream>>>(wq, wk, wv, wqkv_bf);
  conv_plain<<<4096, blk, 0, stream>>>(wo, wo_bf);
  conv_w13<<<22016, blk, 0, stream>>>(w1, w3, w13_bf);
  conv_plain<<<10880, blk, 0, stream>>>(w2, w2_bf);

  rmsnorm_k<<<4096, blk, 0, stream>>>(x, g_attn, h_bf);

  gemm_p<0><<<dim3(32, 48), blk, 0, stream>>>(h_bf, wqkv_bf, q_bf, k_bf, vt_bf,
                                              nullptr, cosT, sinT, 4096, 6144, 2048);

  attn_fwd<<<dim3(16, 16, 2), blk, 0, stream>>>(q_bf, k_bf, vt_bf, o_bf);

  gemm_p<1><<<dim3(32, 16), blk, 0, stream>>>(o_bf, wo_bf, out, nullptr, nullptr,
                                              x, nullptr, nullptr, 4096, 2048, 2048);
  rmsnorm_k<<<4096, blk, 0, stream>>>(out, g_ffn, h_bf);

  gemm8v2<2><<<dim3(688), dim3(512), 0, stream>>>(h_bf, w13_bf, a1_bf, 4096, 11008, 2048);

  gemm_p<3><<<dim3(32, 16), blk, 0, stream>>>(a1_bf, w2_bf, out, nullptr, nullptr,
                                              nullptr, nullptr, nullptr, 4096, 2048, 5440);
}

// Round 15
// 649.994 us; speedup vs baseline: 1.0061x; 1.0061x over previous
//
#include <hip/hip_runtime.h>
#include <cstdint>
#include <cstddef>

typedef float  f32x4  __attribute__((ext_vector_type(4)));
typedef __bf16 bf16x8 __attribute__((ext_vector_type(8)));
typedef unsigned short u16x8 __attribute__((ext_vector_type(8)));
typedef unsigned short u16x4 __attribute__((ext_vector_type(4)));
typedef unsigned short u16x2 __attribute__((ext_vector_type(2)));

#define DEV static __device__ __forceinline__

DEV unsigned short f2bfu(float f) { __bf16 b = (__bf16)f; return __builtin_bit_cast(unsigned short, b); }
DEV float bfu2f(unsigned short u) { return (float)__builtin_bit_cast(__bf16, u); }
DEV bf16x8 ldb8(const void* p) { return __builtin_bit_cast(bf16x8, *(const u16x8*)p); }
DEV float fexp(float x) { return __builtin_amdgcn_exp2f(x * 1.44269504f); }
DEV float fexp2(float x) { return __builtin_amdgcn_exp2f(x); }

DEV f32x4 mfma16(bf16x8 a, bf16x8 b, f32x4 c) {
  return __builtin_amdgcn_mfma_f32_16x16x32_bf16(a, b, c, 0, 0, 0);
}

DEV void gload16(const void* g, void* l) {
  __builtin_amdgcn_global_load_lds((const unsigned int*)g, (unsigned int*)l, 16, 0, 0);
}

#define FENCE() asm volatile("" ::: "memory")
#define LGKM0() asm volatile("s_waitcnt lgkmcnt(0)" ::: "memory")
#define LGKM2() asm volatile("s_waitcnt lgkmcnt(2)" ::: "memory")
#define LGKM4() asm volatile("s_waitcnt lgkmcnt(4)" ::: "memory")
#define VMC8()  asm volatile("s_waitcnt vmcnt(8)" ::: "memory")
#define VMC4()  asm volatile("s_waitcnt vmcnt(4)" ::: "memory")
#define VMC0()  asm volatile("s_waitcnt vmcnt(0)" ::: "memory")
#define SBAR()  __builtin_amdgcn_s_barrier()
#define SCH0()  __builtin_amdgcn_sched_barrier(0)
#define PRIO1() __builtin_amdgcn_s_setprio(1)
#define PRIO0() __builtin_amdgcn_s_setprio(0)

// ---------------------------------------------------------------------------
// Weight conversion kernels (f32 -> bf16), run once per call.
// ---------------------------------------------------------------------------
__global__ __launch_bounds__(256) void conv_cat3(
    const float* __restrict__ s0, const float* __restrict__ s1,
    const float* __restrict__ s2, unsigned short* __restrict__ d)
{
  size_t i = (size_t)blockIdx.x * 256 + threadIdx.x;
  size_t e = i * 4;
  const float* s = e < 4194304 ? s0 : (e < 8388608 ? s1 : s2);
  f32x4 v = *(const f32x4*)(s + (e & 4194303));
  u16x4 o = { f2bfu(v.x), f2bfu(v.y), f2bfu(v.z), f2bfu(v.w) };
  *(u16x4*)(d + e) = o;
}

__global__ __launch_bounds__(256) void conv_plain(
    const float* __restrict__ s, unsigned short* __restrict__ d)
{
  size_t e = ((size_t)blockIdx.x * 256 + threadIdx.x) * 4;
  f32x4 v = *(const f32x4*)(s + e);
  u16x4 o = { f2bfu(v.x), f2bfu(v.y), f2bfu(v.z), f2bfu(v.w) };
  *(u16x4*)(d + e) = o;
}

// interleave w1/w3 rows in 16-row groups: logical row n -> grp=n>>4 even: w1,
// odd: w3, source row (grp>>1)*16 + (n&15). Pads to N=11008 with clamp.
__global__ __launch_bounds__(256) void conv_w13(
    const float* __restrict__ w1, const float* __restrict__ w3,
    unsigned short* __restrict__ d)
{
  size_t i = (size_t)blockIdx.x * 256 + threadIdx.x;
  size_t e = i * 4;
  if (e >= 22544384ull) return;
  int n = (int)(e >> 11), kc = (int)(e & 2047);
  int grp = n >> 4;
  int srcrow = (grp >> 1) * 16 + (n & 15);
  if (srcrow >= 5440) srcrow = 5439;
  const float* s = (grp & 1) ? w3 : w1;
  size_t off = (size_t)srcrow * 2048 + kc;
  f32x4 v = *(const f32x4*)(s + off);
  u16x4 o = { f2bfu(v.x), f2bfu(v.y), f2bfu(v.z), f2bfu(v.w) };
  *(u16x4*)(d + e) = o;
}

// ---------------------------------------------------------------------------
// gemm_p: 128x128 tile, deep pipeline. BK=64 in two 32-col halves, each half
// double-buffered; 2 phases/K-tile, counted vmcnt(4). Counted-lgkm split
// (R14-proven on W13): reads pinned {bfr0-3, af0-1} | {af2-3}; lgkmcnt(2)
// before MFMA half 1 (mi 0-1), lgkmcnt(0) before half 2 (mi 2-3).
// EPI 0: QKV fused + RoPE; EPI 1: OPROJ f32 D0=auxf+acc; EPI 3: W2ACC D0+=acc
// ---------------------------------------------------------------------------
template<int EPI>
__global__ __launch_bounds__(256) void gemm_p(
    const unsigned short* __restrict__ A, const unsigned short* __restrict__ B,
    void* __restrict__ D0, void* __restrict__ D1, void* __restrict__ D2,
    const float* __restrict__ auxf, const float* __restrict__ cosT,
    const float* __restrict__ sinT, int M, int N, int K)
{
  __shared__ __align__(16) char Asb[4 * 8192];   // [kh*2+db]
  __shared__ __align__(16) char Bsb[4 * 8192];

  const int tid = threadIdx.x, lane = tid & 63, w = tid >> 6;
  const int wr = w >> 1, wc = w & 1, l15 = lane & 15, lg = lane >> 4;
  const int m0 = blockIdx.x * 128, n0 = blockIdx.y * 128;

  const int srow = tid >> 2, s4 = tid & 3;
  const int s4s = s4 ^ ((srow >> 1) & 3);
  const unsigned short* As0 = A + (size_t)(m0 + srow) * K + s4s * 8;
  const unsigned short* As1 = A + (size_t)(m0 + 64 + srow) * K + s4s * 8;
  const unsigned short* Bs0 = B + (size_t)(n0 + srow) * K + s4s * 8;
  const unsigned short* Bs1 = B + (size_t)(n0 + 64 + srow) * K + s4s * 8;
  const int dst0 = tid * 16, dst1 = 4096 + tid * 16;

#define STG_A(kh, db, kt) do { char* r = Asb + ((kh)*2+(db))*8192;            \
    gload16(As0 + (size_t)(kt)*64 + (kh)*32, r + dst0);                        \
    gload16(As1 + (size_t)(kt)*64 + (kh)*32, r + dst1); } while(0)
#define STG_B(kh, db, kt) do { char* r = Bsb + ((kh)*2+(db))*8192;            \
    gload16(Bs0 + (size_t)(kt)*64 + (kh)*32, r + dst0);                        \
    gload16(Bs1 + (size_t)(kt)*64 + (kh)*32, r + dst1); } while(0)

  f32x4 zero = {0.f, 0.f, 0.f, 0.f};
  f32x4 acc[4][4];
#pragma unroll
  for (int i = 0; i < 4; i++)
#pragma unroll
    for (int j = 0; j < 4; j++) acc[i][j] = zero;

  int aro[4], bro[4];
#pragma unroll
  for (int mi = 0; mi < 4; mi++) {
    int row = wr * 64 + mi * 16 + l15;
    aro[mi] = row * 64 + ((lg ^ ((row >> 1) & 3)) << 4);
  }
#pragma unroll
  for (int ni = 0; ni < 4; ni++) {
    int row = wc * 64 + ni * 16 + l15;
    bro[ni] = row * 64 + ((lg ^ ((row >> 1) & 3)) << 4);
  }

  const int nkt = K >> 6;

  STG_A(0, 0, 0); STG_B(0, 0, 0); STG_A(1, 0, 0); STG_B(1, 0, 0);

  for (int t = 0; t < nkt; ++t) {
    const int db = t & 1, dn = db ^ 1;
    const bool pf = (t + 1) < nkt;
    const char* Ar0 = Asb + (0 * 2 + db) * 8192;
    const char* Br0 = Bsb + (0 * 2 + db) * 8192;
    const char* Ar1 = Asb + (1 * 2 + db) * 8192;
    const char* Br1 = Bsb + (1 * 2 + db) * 8192;

    // ---- phase 0 (K-half 0)
    VMC4(); FENCE(); SBAR();
    bf16x8 af[4], bfr[4];
#pragma unroll
    for (int ni = 0; ni < 4; ni++) bfr[ni] = ldb8(Br0 + bro[ni]);
    af[0] = ldb8(Ar0 + aro[0]);
    af[1] = ldb8(Ar0 + aro[1]);
    SCH0();                              // pin: first 6 ds_reads stay first
    af[2] = ldb8(Ar0 + aro[2]);
    af[3] = ldb8(Ar0 + aro[3]);
    if (pf) { STG_A(0, dn, t + 1); STG_B(0, dn, t + 1); }
    LGKM2(); SCH0();
    PRIO1();
#pragma unroll
    for (int mi = 0; mi < 2; mi++)
#pragma unroll
      for (int ni = 0; ni < 4; ni++)
        acc[mi][ni] = mfma16(af[mi], bfr[ni], acc[mi][ni]);
    PRIO0();
    LGKM0(); SCH0();
    PRIO1();
#pragma unroll
    for (int mi = 2; mi < 4; mi++)
#pragma unroll
      for (int ni = 0; ni < 4; ni++)
        acc[mi][ni] = mfma16(af[mi], bfr[ni], acc[mi][ni]);
    PRIO0();

    // ---- phase 1 (K-half 1)
    if (pf) { VMC4(); } else { VMC0(); }
    FENCE(); SBAR();
#pragma unroll
    for (int ni = 0; ni < 4; ni++) bfr[ni] = ldb8(Br1 + bro[ni]);
    af[0] = ldb8(Ar1 + aro[0]);
    af[1] = ldb8(Ar1 + aro[1]);
    SCH0();
    af[2] = ldb8(Ar1 + aro[2]);
    af[3] = ldb8(Ar1 + aro[3]);
    if (pf) { STG_A(1, dn, t + 1); STG_B(1, dn, t + 1); }
    LGKM2(); SCH0();
    PRIO1();
#pragma unroll
    for (int mi = 0; mi < 2; mi++)
#pragma unroll
      for (int ni = 0; ni < 4; ni++)
        acc[mi][ni] = mfma16(af[mi], bfr[ni], acc[mi][ni]);
    PRIO0();
    LGKM0(); SCH0();
    PRIO1();
#pragma unroll
    for (int mi = 2; mi < 4; mi++)
#pragma unroll
      for (int ni = 0; ni < 4; ni++)
        acc[mi][ni] = mfma16(af[mi], bfr[ni], acc[mi][ni]);
    PRIO0();
  }
#undef STG_A
#undef STG_B

  if constexpr (EPI == 0) {
    unsigned short* qd = (unsigned short*)D0;
    unsigned short* kd = (unsigned short*)D1;
    unsigned short* vd = (unsigned short*)D2;
#pragma unroll
    for (int mi = 0; mi < 4; mi++) {
#pragma unroll
      for (int ni = 0; ni < 4; ni++) {
        int col = n0 + wc * 64 + ni * 16 + l15;
#pragma unroll
        for (int r = 0; r < 4; r++) {
          int row = m0 + wr * 64 + mi * 16 + lg * 4 + r;
          float v = acc[mi][ni][r];
          if (col < 4096) {
            int d = col & 127, pi = d >> 1, sp = row & 2047;
            float c = cosT[sp * 64 + pi], s = sinT[sp * 64 + pi];
            float part = __shfl_xor(v, 1);
            float res = (d & 1) ? (part * s + v * c) : (v * c - part * s);
            unsigned short* dst = (col < 2048) ? qd : kd;
            dst[(size_t)row * 2048 + (col & 2047)] = f2bfu(res);
          } else {
            int vdc = col - 4096;
            vd[((size_t)((row >> 11) * 2048 + vdc)) * 2048 + (row & 2047)] = f2bfu(v);
          }
        }
      }
    }
  } else {
    float* O = (float*)D0;
#pragma unroll
    for (int mi = 0; mi < 4; mi++)
#pragma unroll
      for (int ni = 0; ni < 4; ni++) {
        int col = n0 + wc * 64 + ni * 16 + l15;
#pragma unroll
        for (int r = 0; r < 4; r++) {
          int row = m0 + wr * 64 + mi * 16 + lg * 4 + r;
          size_t ix = (size_t)row * 2048 + col;
          if constexpr (EPI == 1) O[ix] = auxf[ix] + acc[mi][ni][r];
          else                    O[ix] = O[ix] + acc[mi][ni][r];
        }
      }
  }
}

// ---------------------------------------------------------------------------
// gemm8v2 + counted-lgkm (R14-proven): all 12 ds_reads of a K-half up front;
// lgkmcnt(4) before MFMA quadrant 1, lgkmcnt(0) before quadrant 2.
// EPI 2: GATE13 silu(a)*c epilogue.
// ---------------------------------------------------------------------------
template<int EPI>
__global__ __launch_bounds__(512, 1) void gemm8v2(
    const unsigned short* __restrict__ A, const unsigned short* __restrict__ B,
    void* __restrict__ D0, int M, int N, int K)
{
  __shared__ __align__(16) char Asb[4 * 16384];   // [kh*2+db]
  __shared__ __align__(16) char Bsb[4 * 16384];

  const int tid = threadIdx.x, lane = tid & 63, w = tid >> 6;
  const int wm = w >> 2, wn = w & 3;
  const int l15 = lane & 15, lg = lane >> 4;

  const int nwg = gridDim.x, chunk = nwg >> 3;
  const int wg = (blockIdx.x & 7) * chunk + (blockIdx.x >> 3);
  const int MT = M >> 8;
  const int mt = wg % MT, nt = wg / MT;
  const int m0 = mt * 256, n0 = nt * 256;

  const int srow = tid >> 2;
  const int s4   = tid & 3;
  const int s4s  = s4 ^ ((srow >> 1) & 3);
  const unsigned short* As0 = A + (size_t)(m0 + srow) * K + s4s * 8;
  const unsigned short* As1 = A + (size_t)(m0 + 128 + srow) * K + s4s * 8;
  const unsigned short* Bs0 = B + (size_t)(n0 + srow) * K + s4s * 8;
  const unsigned short* Bs1 = B + (size_t)(n0 + 128 + srow) * K + s4s * 8;
  const int dst0 = tid * 16, dst1 = 8192 + tid * 16;

#define STAGE_A(kh, db, kt) do { char* rgn = Asb + ((kh)*2+(db))*16384;       \
    gload16(As0 + (size_t)(kt)*64 + (kh)*32, rgn + dst0);                      \
    gload16(As1 + (size_t)(kt)*64 + (kh)*32, rgn + dst1); } while(0)
#define STAGE_B(kh, db, kt) do { char* rgn = Bsb + ((kh)*2+(db))*16384;       \
    gload16(Bs0 + (size_t)(kt)*64 + (kh)*32, rgn + dst0);                      \
    gload16(Bs1 + (size_t)(kt)*64 + (kh)*32, rgn + dst1); } while(0)

  f32x4 zero = {0.f, 0.f, 0.f, 0.f};
  f32x4 acc[8][4];
#pragma unroll
  for (int i = 0; i < 8; i++)
#pragma unroll
    for (int j = 0; j < 4; j++) acc[i][j] = zero;

  int aro[8], bro[4];
#pragma unroll
  for (int mi = 0; mi < 8; mi++) {
    int row = wm * 128 + mi * 16 + l15;
    aro[mi] = row * 64 + ((lg ^ ((row >> 1) & 3)) << 4);
  }
#pragma unroll
  for (int ni = 0; ni < 4; ni++) {
    int row = wn * 64 + ni * 16 + l15;
    bro[ni] = row * 64 + ((lg ^ ((row >> 1) & 3)) << 4);
  }

  const int nkt = K >> 6;

  STAGE_A(0, 0, 0); STAGE_B(0, 0, 0); STAGE_A(1, 0, 0); STAGE_B(1, 0, 0);

  for (int t = 0; t < nkt; ++t) {
    const int db = t & 1, dn = db ^ 1;
    const bool pf = (t + 1) < nkt;
    const char* Ar0 = Asb + (0 * 2 + db) * 16384;
    const char* Br0 = Bsb + (0 * 2 + db) * 16384;
    const char* Ar1 = Asb + (1 * 2 + db) * 16384;
    const char* Br1 = Bsb + (1 * 2 + db) * 16384;

    // ---- K-half 0: issue all 12 ds_reads, counted lgkm
    VMC4(); FENCE(); SBAR();
    bf16x8 bfr[4], af[4], ag[4];
#pragma unroll
    for (int ni = 0; ni < 4; ni++) bfr[ni] = ldb8(Br0 + bro[ni]);
#pragma unroll
    for (int mi = 0; mi < 4; mi++) af[mi] = ldb8(Ar0 + aro[mi]);
#pragma unroll
    for (int mi = 0; mi < 4; mi++) ag[mi] = ldb8(Ar0 + aro[mi + 4]);
    if (pf) STAGE_A(0, dn, t + 1);
    LGKM4(); SCH0();
    PRIO1();
#pragma unroll
    for (int mi = 0; mi < 4; mi++)
#pragma unroll
      for (int ni = 0; ni < 4; ni++)
        acc[mi][ni] = mfma16(af[mi], bfr[ni], acc[mi][ni]);
    PRIO0();
    if (pf) STAGE_B(0, dn, t + 1);
    LGKM0(); SCH0();
    PRIO1();
#pragma unroll
    for (int mi = 0; mi < 4; mi++)
#pragma unroll
      for (int ni = 0; ni < 4; ni++)
        acc[mi + 4][ni] = mfma16(ag[mi], bfr[ni], acc[mi + 4][ni]);
    PRIO0();

    // ---- K-half 1
    if (pf) { VMC4(); } else { VMC0(); }
    FENCE(); SBAR();
#pragma unroll
    for (int ni = 0; ni < 4; ni++) bfr[ni] = ldb8(Br1 + bro[ni]);
#pragma unroll
    for (int mi = 0; mi < 4; mi++) af[mi] = ldb8(Ar1 + aro[mi]);
#pragma unroll
    for (int mi = 0; mi < 4; mi++) ag[mi] = ldb8(Ar1 + aro[mi + 4]);
    if (pf) STAGE_A(1, dn, t + 1);
    LGKM4(); SCH0();
    PRIO1();
#pragma unroll
    for (int mi = 0; mi < 4; mi++)
#pragma unroll
      for (int ni = 0; ni < 4; ni++)
        acc[mi][ni] = mfma16(af[mi], bfr[ni], acc[mi][ni]);
    PRIO0();
    if (pf) STAGE_B(1, dn, t + 1);
    LGKM0(); SCH0();
    PRIO1();
#pragma unroll
    for (int mi = 0; mi < 4; mi++)
#pragma unroll
      for (int ni = 0; ni < 4; ni++)
        acc[mi + 4][ni] = mfma16(ag[mi], bfr[ni], acc[mi + 4][ni]);
    PRIO0();
  }
#undef STAGE_A
#undef STAGE_B

  if constexpr (EPI == 2) {
    unsigned short* G = (unsigned short*)D0;
#pragma unroll
    for (int mi = 0; mi < 8; mi++)
#pragma unroll
      for (int nj = 0; nj < 2; nj++) {
        int outc = (nt * 8 + wn * 2 + nj) * 16 + l15;
        if (outc >= 5440) continue;
#pragma unroll
        for (int r = 0; r < 4; r++) {
          int row = m0 + wm * 128 + mi * 16 + lg * 4 + r;
          float a = acc[mi][2 * nj][r];
          float c = acc[mi][2 * nj + 1][r];
          float sg = a / (1.0f + fexp(-a));
          G[(size_t)row * 5440 + outc] = f2bfu(sg * c);
        }
      }
  }
}

// ---------------------------------------------------------------------------
// RMSNorm v2: wave-shuffle reduce + one barrier.
// ---------------------------------------------------------------------------
__global__ __launch_bounds__(256) void rmsnorm_k(
    const float* __restrict__ x, const float* __restrict__ g,
    unsigned short* __restrict__ out)
{
  int row = blockIdx.x, t = threadIdx.x;
  const int w = t >> 6;
  const float* xr = x + (size_t)row * 2048;
  f32x4 v0 = ((const f32x4*)xr)[t];
  f32x4 v1 = ((const f32x4*)xr)[t + 256];
  float ss = v0.x*v0.x + v0.y*v0.y + v0.z*v0.z + v0.w*v0.w
           + v1.x*v1.x + v1.y*v1.y + v1.z*v1.z + v1.w*v1.w;
#pragma unroll
  for (int off = 1; off < 64; off <<= 1) ss += __shfl_xor(ss, off);
  __shared__ float red[4];
  if ((t & 63) == 0) red[w] = ss;
  __syncthreads();
  float tot = red[0] + red[1] + red[2] + red[3];
  float rinv = rsqrtf(tot * (1.0f / 2048.0f) + 1e-5f);
  f32x4 g0 = ((const f32x4*)g)[t];
  f32x4 g1 = ((const f32x4*)g)[t + 256];
  u16x4 o0 = { f2bfu(v0.x*rinv*g0.x), f2bfu(v0.y*rinv*g0.y),
               f2bfu(v0.z*rinv*g0.z), f2bfu(v0.w*rinv*g0.w) };
  u16x4 o1 = { f2bfu(v1.x*rinv*g1.x), f2bfu(v1.y*rinv*g1.y),
               f2bfu(v1.z*rinv*g1.z), f2bfu(v1.w*rinv*g1.w) };
  *(u16x4*)(out + (size_t)row * 2048 + t * 4) = o0;
  *(u16x4*)(out + (size_t)row * 2048 + 1024 + t * 4) = o1;
}

__global__ __launch_bounds__(256) void rope_tab(float* __restrict__ cosT,
                                                float* __restrict__ sinT)
{
  int idx = blockIdx.x * 256 + threadIdx.x;
  int s = idx >> 6, p = idx & 63;
  float ang = (float)s * powf(10000.0f, -(float)p / 64.0f);
  cosT[idx] = cosf(ang);
  sinT[idx] = sinf(ang);
}

// ---------------------------------------------------------------------------
// Flash attention (R10 best-known form). Causal, swapped QK^T, KVBLK=64,
// 4 waves/block, paired q-tiles {bx, 31-bx}, K/V via global_load_lds into
// dbuf LDS, counted vmcnt(8), setprio on MFMA. Raw-score softmax
// (C = scale*log2e folded into exp2); defer-max (T13); rcp epilogue.
// ---------------------------------------------------------------------------
__global__ __launch_bounds__(256) void attn_fwd(
    const unsigned short* __restrict__ q, const unsigned short* __restrict__ k,
    const unsigned short* __restrict__ vt, unsigned short* __restrict__ o)
{
  const int S = 2048, Dm = 2048;
  const int tid  = threadIdx.x;
  const int lane = tid & 63;
  const int w    = tid >> 6;
  const int hh   = blockIdx.y, b = blockIdx.z;
  const int l15  = lane & 15, lg = lane >> 4;
  const float C = 0.08838834764831845f * 1.44269504f;  // scale * log2(e)

  __shared__ __align__(16) char Ksb[2][16384];
  __shared__ __align__(16) char Vsb[2][16384];
  __shared__ __align__(16) unsigned short Ps[4][16 * 76];

  const unsigned short* kg = k  + ((size_t)(b * S)) * Dm + hh * 128;
  const unsigned short* vg = vt + ((size_t)((b * 16 + hh) * 128)) * S;

  const int krs = tid >> 4, ksp = (tid & 15) ^ (krs & 7);
  const int vrs = tid >> 3, vsp = (tid & 7) ^ (vrs & 7);

#define STAGE_KV(j, buf) do {                                                  \
    int kv_ = (j) * 64;                                                        \
    _Pragma("unroll")                                                          \
    for (int rr = 0; rr < 4; rr++)                                             \
      gload16(kg + (size_t)(kv_ + rr * 16 + krs) * 2048 + ksp * 8,             \
              Ksb[buf] + (rr * 256 + tid) * 16);                               \
    _Pragma("unroll")                                                          \
    for (int rr = 0; rr < 4; rr++)                                             \
      gload16(vg + (size_t)(rr * 32 + vrs) * 2048 + kv_ + vsp * 8,             \
              Vsb[buf] + (rr * 256 + tid) * 16);                               \
  } while (0)

  for (int half = 0; half < 2; ++half) {
    const int qt = half ? (31 - blockIdx.x) : blockIdx.x;
    const int r0 = qt * 64;
    const int myq = r0 + w * 16 + l15;

    STAGE_KV(0, 0);

    bf16x8 qf[4];
    size_t qbase = ((size_t)(b * S + r0 + w * 16 + l15)) * Dm + hh * 128 + lg * 8;
#pragma unroll
    for (int kk = 0; kk < 4; kk++) qf[kk] = ldb8(q + qbase + kk * 32);

    f32x4 zero = {0.f, 0.f, 0.f, 0.f};
    f32x4 accO[8];
#pragma unroll
    for (int dt = 0; dt < 8; dt++) accO[dt] = zero;
    float mrun = -1e30f, lrun = 0.f;   // RAW (unscaled) units

    int ntile = qt + 1;
    for (int j = 0; j < ntile; ++j) {
      int kv0 = j * 64;
      const int db = j & 1;
      const bool pf = (j + 1) < ntile;
      if (pf) STAGE_KV(j + 1, db ^ 1);
      if (pf) { VMC8(); } else { VMC0(); }
      FENCE(); SBAR();

      const char* Ks = Ksb[db];
      const char* Vs = Vsb[db];

      f32x4 sfr[4];
#pragma unroll
      for (int sv = 0; sv < 4; sv++) sfr[sv] = zero;
      PRIO1();
#pragma unroll
      for (int kk = 0; kk < 4; kk++) {
#pragma unroll
        for (int sv = 0; sv < 4; sv++) {
          int row = sv * 16 + l15;
          int boff = (row * 256 + kk * 64 + lg * 16) ^ ((row & 7) << 4);
          bf16x8 kf = ldb8(Ks + boff);
          sfr[sv] = mfma16(kf, qf[kk], sfr[sv]);
        }
      }
      PRIO0();

      float tmax = -1e30f;
#pragma unroll
      for (int sv = 0; sv < 4; sv++)
#pragma unroll
        for (int r = 0; r < 4; r++) {
          int kvv = kv0 + sv * 16 + lg * 4 + r;
          float val = (kvv <= myq) ? sfr[sv][r] : -1e30f;
          sfr[sv][r] = val;
          tmax = fmaxf(tmax, val);
        }
      tmax = fmaxf(tmax, __shfl_xor(tmax, 16));
      tmax = fmaxf(tmax, __shfl_xor(tmax, 32));

      if (!__all(tmax <= mrun + 64.0f)) {
        float mnew = fmaxf(mrun, tmax);
        float alpha = fexp2((mrun - mnew) * C);
        lrun *= alpha;
        mrun = mnew;
        float al[4];
#pragma unroll
        for (int r = 0; r < 4; r++)
          al[r] = __shfl(alpha, (lane & 48) + lg * 4 + r);
#pragma unroll
        for (int dt = 0; dt < 8; dt++) {
          f32x4 t = accO[dt];
          t[0] *= al[0]; t[1] *= al[1]; t[2] *= al[2]; t[3] *= al[3];
          accO[dt] = t;
        }
      }

      float psum = 0.f;
#pragma unroll
      for (int sv = 0; sv < 4; sv++)
#pragma unroll
        for (int r = 0; r < 4; r++) {
          float pvv = fexp2((sfr[sv][r] - mrun) * C);
          sfr[sv][r] = pvv;
          psum += pvv;
        }
      psum += __shfl_xor(psum, 16);
      psum += __shfl_xor(psum, 32);
      lrun += psum;

#pragma unroll
      for (int sv = 0; sv < 4; sv++) {
        u16x2 lo = { f2bfu(sfr[sv][0]), f2bfu(sfr[sv][1]) };
        u16x2 hi = { f2bfu(sfr[sv][2]), f2bfu(sfr[sv][3]) };
        *(u16x2*)&Ps[w][l15 * 76 + sv * 16 + lg * 4]     = lo;
        *(u16x2*)&Ps[w][l15 * 76 + sv * 16 + lg * 4 + 2] = hi;
      }

      bf16x8 pa[2];
      pa[0] = ldb8(&Ps[w][l15 * 76 + lg * 8]);
      pa[1] = ldb8(&Ps[w][l15 * 76 + 32 + lg * 8]);
      PRIO1();
#pragma unroll
      for (int dt = 0; dt < 8; dt++) {
#pragma unroll
        for (int kk = 0; kk < 2; kk++) {
          int row = dt * 16 + l15;
          int boff = (row * 128 + kk * 64 + lg * 16) ^ ((row & 7) << 4);
          bf16x8 vb = ldb8(Vs + boff);
          accO[dt] = mfma16(pa[kk], vb, accO[dt]);
        }
      }
      PRIO0();
      FENCE(); SBAR();
    }

    float lf[4];
#pragma unroll
    for (int r = 0; r < 4; r++) {
      float lv = __shfl(lrun, (lane & 48) + lg * 4 + r);
      lf[r] = __builtin_amdgcn_rcpf(lv);
    }
#pragma unroll
    for (int dt = 0; dt < 8; dt++) {
#pragma unroll
      for (int r = 0; r < 4; r++) {
        int qr = r0 + w * 16 + lg * 4 + r;
        o[((size_t)(b * S + qr)) * Dm + hh * 128 + dt * 16 + l15] =
            f2bfu(accO[dt][r] * lf[r]);
      }
    }
  }
#undef STAGE_KV
}

// ---------------------------------------------------------------------------
extern "C" void kernel_launch(void* const* d_in, const int* in_sizes, int n_in,
                              void* d_out, int out_size, void* d_ws, size_t ws_size,
                              hipStream_t stream)
{
  const float* x      = (const float*)d_in[0];
  const float* wq     = (const float*)d_in[1];
  const float* wk     = (const float*)d_in[2];
  const float* wv     = (const float*)d_in[3];
  const float* wo     = (const float*)d_in[4];
  const float* w1     = (const float*)d_in[5];
  const float* w2     = (const float*)d_in[6];
  const float* w3     = (const float*)d_in[7];
  const float* g_attn = (const float*)d_in[8];
  const float* g_ffn  = (const float*)d_in[9];
  float* out = (float*)d_out;

  unsigned short* W = (unsigned short*)d_ws;
  unsigned short* h_bf    = W;                      // 8388608
  unsigned short* q_bf    = W + 8388608ull;
  unsigned short* k_bf    = W + 16777216ull;
  unsigned short* vt_bf   = W + 25165824ull;
  unsigned short* o_bf    = W + 33554432ull;
  unsigned short* wqkv_bf = W + 41943040ull;        // 12582912
  unsigned short* wo_bf   = W + 54525952ull;        // 4194304
  unsigned short* w13_bf  = W + 58720256ull;        // 22544384 (11008 x 2048)
  unsigned short* w2_bf   = W + 81264640ull;        // 11141120
  unsigned short* a1_bf   = q_bf;                   // alias: q/k/vt dead by then
  float* cosT = (float*)o_bf;                       // consumed before o written
  float* sinT = cosT + 131072;

  dim3 blk(256);
  rope_tab<<<512, blk, 0, stream>>>(cosT, sinT);
  conv_cat3<<<12288, blk, 0, stream>>>(wq, wk, wv, wqkv_bf);
  conv_plain<<<4096, blk, 0, stream>>>(wo, wo_bf);
  conv_w13<<<22016, blk, 0, stream>>>(w1, w3, w13_bf);
  conv_plain<<<10880, blk, 0, stream>>>(w2, w2_bf);

  rmsnorm_k<<<4096, blk, 0, stream>>>(x, g_attn, h_bf);

  gemm_p<0><<<dim3(32, 48), blk, 0, stream>>>(h_bf, wqkv_bf, q_bf, k_bf, vt_bf,
                                              nullptr, cosT, sinT, 4096, 6144, 2048);

  attn_fwd<<<dim3(16, 16, 2), blk, 0, stream>>>(q_bf, k_bf, vt_bf, o_bf);

  gemm_p<1><<<dim3(32, 16), blk, 0, stream>>>(o_bf, wo_bf, out, nullptr, nullptr,
                                              x, nullptr, nullptr, 4096, 2048, 2048);
  rmsnorm_k<<<4096, blk, 0, stream>>>(out, g_ffn, h_bf);

  gemm8v2<2><<<dim3(688), dim3(512), 0, stream>>>(h_bf, w13_bf, a1_bf, 4096, 11008, 2048);

  gemm_p<3><<<dim3(32, 16), blk, 0, stream>>>(a1_bf, w2_bf, out, nullptr, nullptr,
                                              nullptr, nullptr, nullptr, 4096, 2048, 5440);
}